// Round 10
// baseline (336.140 us; speedup 1.0000x reference)
//
#include <hip/hip_runtime.h>
#include <math.h>

#define N_NODES 100000
#define N_EDGES 1600000
#define DIM 32
#define N_GROUPS 64
#define BN_EPS 1e-5f

#define BIN_NODES 128
#define NBINS ((N_NODES + BIN_NODES - 1) / BIN_NODES)   // 782
#define EPB_HIST 8192
#define HIST_BLOCKS ((N_EDGES + EPB_HIST - 1) / EPB_HIST)  // 196

typedef __attribute__((ext_vector_type(8))) short short8;   // 8 bf16 (4 VGPRs)
typedef __attribute__((ext_vector_type(4))) float f32x4;

// ---- monotone float<->uint encoding for atomic max on floats ----
__device__ __forceinline__ unsigned enc_f32(float f) {
    unsigned u = __float_as_uint(f);
    return (u & 0x80000000u) ? ~u : (u | 0x80000000u);
}
__device__ __forceinline__ float dec_f32(unsigned u) {
    return (u & 0x80000000u) ? __uint_as_float(u & 0x7FFFFFFFu) : __uint_as_float(~u);
}
// fp32 -> bf16 bits (RNE)
__device__ __forceinline__ unsigned short f2bf(float f) {
    unsigned u = __float_as_uint(f);
    u += 0x7FFFu + ((u >> 16) & 1u);
    return (unsigned short)(u >> 16);
}
__device__ __forceinline__ float bf2f(unsigned short s) {
    return __uint_as_float((unsigned)s << 16);
}

// Fold BN into weights; also emit bf16 copy of folded W for the MFMA paths.
__global__ void fold_kernel(const float* __restrict__ lin_W, const float* __restrict__ lin_b,
                            const float* __restrict__ lin_gamma, const float* __restrict__ lin_beta,
                            const float* __restrict__ lin_mean, const float* __restrict__ lin_var,
                            const float* __restrict__ conv_W, const float* __restrict__ conv_b,
                            const float* __restrict__ conv_gamma, const float* __restrict__ conv_beta,
                            const float* __restrict__ conv_mean, const float* __restrict__ conv_var,
                            float* __restrict__ Wf, float* __restrict__ shf,
                            unsigned short* __restrict__ Wfb)
{
    int l = blockIdx.x;      // 0..2 = lin, 3..4 = conv
    int t = threadIdx.x;
    const float *W, *b, *gm, *bt, *mn, *vr;
    if (l < 3) {
        W = lin_W + l * DIM * DIM; b = lin_b + l * DIM; gm = lin_gamma + l * DIM;
        bt = lin_beta + l * DIM;   mn = lin_mean + l * DIM; vr = lin_var + l * DIM;
    } else {
        int c = l - 3;
        W = conv_W + c * DIM * DIM; b = conv_b + c * DIM; gm = conv_gamma + c * DIM;
        bt = conv_beta + c * DIM;   mn = conv_mean + c * DIM; vr = conv_var + c * DIM;
    }
    int j = t & (DIM - 1);
    float scale = gm[j] / sqrtf(vr[j] + BN_EPS);
    float w = W[t] * scale;
    Wf[l * DIM * DIM + t] = w;
    Wfb[l * DIM * DIM + t] = f2bf(w);
    if (t < DIM) shf[l * DIM + t] = (b[t] - mn[t]) * scale + bt[t];
}

// x (fp32) -> xb (bf16 bits), 4 elems/thread
__global__ __launch_bounds__(256) void convert_kernel(const float* __restrict__ x,
                                                      unsigned short* __restrict__ xb) {
    int i = blockIdx.x * 256 + threadIdx.x;          // grid exact: N*DIM/4/256
    float4 v = ((const float4*)x)[i];
    uint2 o;
    o.x = (unsigned)f2bf(v.x) | ((unsigned)f2bf(v.y) << 16);
    o.y = (unsigned)f2bf(v.z) | ((unsigned)f2bf(v.w) << 16);
    ((uint2*)xb)[i] = o;
}

// ================= bin-grouped edge build (unchanged, proven) =================
__global__ __launch_bounds__(256) void binhist_kernel(const int* __restrict__ dst,
                                                      int* __restrict__ bincnt,
                                                      int* __restrict__ blockcnt) {
    __shared__ int cnt[NBINS];
    int t = threadIdx.x;
    for (int b = t; b < NBINS; b += 256) cnt[b] = 0;
    __syncthreads();
    int base = blockIdx.x * EPB_HIST;
    for (int i = 0; i < EPB_HIST / 256; ++i) {
        int e = base + i * 256 + t;
        if (e < N_EDGES) atomicAdd(&cnt[dst[e] >> 7], 1);
    }
    __syncthreads();
    for (int b = t; b < NBINS; b += 256) {
        int c = cnt[b];
        blockcnt[(size_t)blockIdx.x * NBINS + b] = c;
        if (c > 0) atomicAdd(&bincnt[b], c);
    }
}

__global__ __launch_bounds__(1024) void binscan_kernel(const int* __restrict__ bincnt,
                                                       int* __restrict__ binoff,
                                                       int* __restrict__ bincur) {
    __shared__ int s[1024];
    int t = threadIdx.x;
    int c = (t < NBINS) ? bincnt[t] : 0;
    s[t] = c;
    __syncthreads();
    for (int off = 1; off < 1024; off <<= 1) {
        int u = (t >= off) ? s[t - off] : 0;
        __syncthreads();
        s[t] += u;
        __syncthreads();
    }
    if (t < NBINS) { binoff[t] = s[t] - c; bincur[t] = s[t] - c; }
    if (t == 0) binoff[NBINS] = N_EDGES;
}

__global__ __launch_bounds__(256) void binscatter_kernel(const int* __restrict__ src,
                                                         const int* __restrict__ dst,
                                                         int* __restrict__ bincur,
                                                         unsigned* __restrict__ binbuf,
                                                         const int* __restrict__ blockcnt) {
    __shared__ int pos[NBINS];
    int t = threadIdx.x;
    for (int b = t; b < NBINS; b += 256) {
        int c = blockcnt[(size_t)blockIdx.x * NBINS + b];
        pos[b] = (c > 0) ? atomicAdd(&bincur[b], c) : 0;
    }
    __syncthreads();
    int base = blockIdx.x * EPB_HIST;
    for (int i = 0; i < EPB_HIST / 256; ++i) {
        int e = base + i * 256 + t;
        if (e < N_EDGES) {
            int d = dst[e];
            int bin = d >> 7;
            int p = atomicAdd(&pos[bin], 1);
            binbuf[p] = ((unsigned)(d & 127) << 17) | (unsigned)src[e];
        }
    }
}

// counting sort within bin -> exact per-node CSR
__global__ __launch_bounds__(256) void binsort_kernel(const unsigned* __restrict__ binbuf,
                                                      const int* __restrict__ binoff,
                                                      int* __restrict__ esrc,
                                                      int* __restrict__ nodeptr) {
    __shared__ int cnt[BIN_NODES];
    __shared__ int sc[BIN_NODES];
    int t = threadIdx.x;
    int bin = blockIdx.x;
    int beg = binoff[bin], end = binoff[bin + 1];
    if (t < BIN_NODES) cnt[t] = 0;
    __syncthreads();
    for (int e = beg + t; e < end; e += 256)
        atomicAdd(&cnt[binbuf[e] >> 17], 1);
    __syncthreads();
    int v = (t < BIN_NODES) ? cnt[t] : 0;
    if (t < BIN_NODES) sc[t] = v;
    __syncthreads();
    for (int off = 1; off < BIN_NODES; off <<= 1) {
        int u = (t < BIN_NODES && t >= off) ? sc[t - off] : 0;
        __syncthreads();
        if (t < BIN_NODES) sc[t] += u;
        __syncthreads();
    }
    if (t < BIN_NODES) {
        int excl = sc[t] - v;
        cnt[t] = excl;
        nodeptr[bin * BIN_NODES + t] = beg + excl;
    }
    __syncthreads();
    for (int e = beg + t; e < end; e += 256) {
        unsigned pe = binbuf[e];
        int dl = (int)(pe >> 17);
        int p = atomicAdd(&cnt[dl], 1);
        esrc[beg + p] = (int)(pe & 0x1FFFFu);
    }
}

// ===== fully fused GIN layer: per-lane-column gather (no reduce) + MFMA conv + MFMA lin
//       + Z accumulate + hierarchical segment-max. Block = 256 thr = 4 waves;
//       each wave owns 16 nodes (one MFMA tile). No cross-wave dependencies except segloc.
__global__ __launch_bounds__(256) void gin_fused_kernel(
        const unsigned short* __restrict__ xb,    // [N,32] bf16 layer input (padded)
        const int* __restrict__ esrc,
        const int* __restrict__ nodeptr,          // [>=N+1] monotone
        const unsigned short* __restrict__ Wcb, const float* __restrict__ shc,
        const unsigned short* __restrict__ Wlb, const float* __restrict__ shl,
        const int* __restrict__ batch, const float* __restrict__ lw_ptr,
        unsigned short* __restrict__ xnextb,      // bf16 mirror out (may be null)
        float* __restrict__ xoutf,                // fp32 conv out (may be null)
        float* __restrict__ Z,                    // [N,32] +=
        unsigned* __restrict__ segmax)            // [G,32] encoded
{
    __shared__ __align__(16) unsigned short hl[4][16 * DIM];   // per-wave tile, bf16
    __shared__ unsigned segloc[8 * DIM];
    int t = threadIdx.x;
    segloc[t] = 0;                     // 256 entries, block is 256

    int wv = t >> 6, lane = t & 63;
    int col = lane & 31, slot = lane >> 5;
    int m = lane & 15, kg = lane >> 4;

    // B fragments: B[k=kg*8+j][n]
    short8 bc0, bc1, bl0, bl1;
#pragma unroll
    for (int j = 0; j < 8; ++j) {
        int k = kg * 8 + j;
        bc0[j] = (short)Wcb[k * DIM + m];
        bc1[j] = (short)Wcb[k * DIM + 16 + m];
        bl0[j] = (short)Wlb[k * DIM + m];
        bl1[j] = (short)Wlb[k * DIM + 16 + m];
    }
    float shc0 = shc[m], shc1 = shc[m + 16];
    float shl0 = shl[m], shl1 = shl[m + 16];
    float lw = lw_ptr[0];
    int blk0 = blockIdx.x * 64;
    int gfirst = batch[blk0];
    int row0 = blk0 + wv * 16;
    __syncthreads();   // segloc init visible

    // ---- gather phase: 16 nodes, lane owns (slot, col); no cross-lane reduce ----
    for (int i = 0; i < 16; ++i) {
        int n = row0 + i;
        float acc = bf2f(xb[(size_t)n * DIM + col]);   // self row (pad covers OOB tail)
        if (slot) acc = 0.f;                           // count self once
        int beg = nodeptr[n], end = nodeptr[n + 1];
        int e = beg + slot;
        for (; e + 2 < end; e += 4) {                  // 2 indep gathers in flight/slot
            int s0 = esrc[e], s1 = esrc[e + 2];
            float v0 = bf2f(xb[(size_t)s0 * DIM + col]);
            float v1 = bf2f(xb[(size_t)s1 * DIM + col]);
            acc += v0; acc += v1;
        }
        for (; e < end; e += 2) acc += bf2f(xb[(size_t)esrc[e] * DIM + col]);
        acc += __shfl_xor(acc, 32, 64);                // fold the two slots
        if (slot == 0) hl[wv][i * DIM + col] = f2bf(acc);
    }

    // ---- conv MLP via MFMA: hp = elu(h @ Wc + shc) ----
    short8 a = *(const short8*)&hl[wv][m * DIM + kg * 8];
    f32x4 d0 = {0.f, 0.f, 0.f, 0.f}, d1 = {0.f, 0.f, 0.f, 0.f};
    d0 = __builtin_amdgcn_mfma_f32_16x16x32_bf16(a, bc0, d0, 0, 0, 0);
    d1 = __builtin_amdgcn_mfma_f32_16x16x32_bf16(a, bc1, d1, 0, 0, 0);
    float hp0[4], hp1[4];
#pragma unroll
    for (int r = 0; r < 4; ++r) {
        float a0 = d0[r] + shc0, a1 = d1[r] + shc1;
        hp0[r] = a0 > 0.f ? a0 : expm1f(a0);
        hp1[r] = a1 > 0.f ? a1 : expm1f(a1);
    }
    // write hp (bf16) back into hl for the lin A-frag (same-wave LDS: in-order safe)
#pragma unroll
    for (int r = 0; r < 4; ++r) {
        hl[wv][(kg * 4 + r) * DIM + m] = f2bf(hp0[r]);
        hl[wv][(kg * 4 + r) * DIM + 16 + m] = f2bf(hp1[r]);
    }
    if (xoutf) {           // layer 2: fp32 conv output is a required output
#pragma unroll
        for (int r = 0; r < 4; ++r) {
            int row = row0 + kg * 4 + r;
            if (row < N_NODES) {
                xoutf[(size_t)row * DIM + m] = hp0[r];
                xoutf[(size_t)row * DIM + 16 + m] = hp1[r];
            }
        }
    }
    if (xnextb) {          // layer 1: bf16 mirror for next layer, coalesced from LDS
        uint4 pk = *(const uint4*)&hl[wv][lane * 8];
        *(uint4*)(xnextb + (size_t)row0 * DIM + lane * 8) = pk;
    }

    // ---- lin MLP via MFMA: z = elu(hp @ Wl + shl); Z += lw*z; segment-max ----
    short8 a2 = *(const short8*)&hl[wv][m * DIM + kg * 8];
    f32x4 e0 = {0.f, 0.f, 0.f, 0.f}, e1 = {0.f, 0.f, 0.f, 0.f};
    e0 = __builtin_amdgcn_mfma_f32_16x16x32_bf16(a2, bl0, e0, 0, 0, 0);
    e1 = __builtin_amdgcn_mfma_f32_16x16x32_bf16(a2, bl1, e1, 0, 0, 0);
#pragma unroll
    for (int r = 0; r < 4; ++r) {
        int row = row0 + kg * 4 + r;
        if (row < N_NODES) {
            float a0 = e0[r] + shl0, a1 = e1[r] + shl1;
            float z0 = a0 > 0.f ? a0 : expm1f(a0);
            float z1 = a1 > 0.f ? a1 : expm1f(a1);
            float zw0 = lw * z0, zw1 = lw * z1;
            size_t zi = (size_t)row * DIM;
            Z[zi + m] += zw0;
            Z[zi + 16 + m] += zw1;
            int g = batch[row];
            int go = g - gfirst;
            if (go < 8) {
                atomicMax(&segloc[go * DIM + m], enc_f32(zw0));
                atomicMax(&segloc[go * DIM + 16 + m], enc_f32(zw1));
            } else {
                atomicMax(&segmax[g * DIM + m], enc_f32(zw0));
                atomicMax(&segmax[g * DIM + 16 + m], enc_f32(zw1));
            }
        }
    }
    __syncthreads();
    unsigned v = segloc[t];
    if (v) atomicMax(&segmax[(gfirst + (t >> 5)) * DIM + (t & 31)], v);
}

// ===== layer-0 lin MLP via MFMA (R9, proven) =====
#define LINM_ROWS_PER_BLOCK 256
__global__ __launch_bounds__(256) void linZ_first_kernel(
        const unsigned short* __restrict__ hb,   // [N,32] bf16 bits
        const unsigned short* __restrict__ Wb,   // [32,32] bf16 folded lin W
        const float* __restrict__ shf,           // [32] fp32 shift
        const int* __restrict__ batch,           // [N] sorted
        const float* __restrict__ lw_ptr,
        float* __restrict__ Z,                   // [N,32] write
        unsigned* __restrict__ segmax)           // [G,32] encoded
{
    __shared__ unsigned segloc[8 * DIM];
    int t = threadIdx.x;
    segloc[t] = 0;

    int wv = t >> 6, lane = t & 63;
    int m = lane & 15;
    int kg = lane >> 4;

    short8 b0, b1;
#pragma unroll
    for (int j = 0; j < 8; ++j) {
        int k = kg * 8 + j;
        b0[j] = (short)Wb[k * DIM + m];
        b1[j] = (short)Wb[k * DIM + 16 + m];
    }
    float sh0 = shf[m], sh1 = shf[m + 16];
    float lw = lw_ptr[0];
    int blk0 = blockIdx.x * LINM_ROWS_PER_BLOCK;
    int gfirst = batch[blk0];
    __syncthreads();

    int r0 = blk0 + wv * 64;
    for (int tile = 0; tile < 4; ++tile) {
        int row0 = r0 + tile * 16;
        if (row0 >= N_NODES) break;               // N%16==0
        short8 a = *(const short8*)(hb + (size_t)(row0 + m) * DIM + kg * 8);
        f32x4 d0 = {0.f, 0.f, 0.f, 0.f}, d1 = {0.f, 0.f, 0.f, 0.f};
        d0 = __builtin_amdgcn_mfma_f32_16x16x32_bf16(a, b0, d0, 0, 0, 0);
        d1 = __builtin_amdgcn_mfma_f32_16x16x32_bf16(a, b1, d1, 0, 0, 0);
#pragma unroll
        for (int r = 0; r < 4; ++r) {
            int row = row0 + kg * 4 + r;
            float a0 = d0[r] + sh0;
            float a1 = d1[r] + sh1;
            float z0 = a0 > 0.f ? a0 : expm1f(a0);
            float z1 = a1 > 0.f ? a1 : expm1f(a1);
            size_t zi = (size_t)row * DIM;
            Z[zi + m] = lw * z0;
            Z[zi + 16 + m] = lw * z1;
            int g = batch[row];
            int go = g - gfirst;
            if (go < 8) {
                atomicMax(&segloc[go * DIM + m], enc_f32(z0));
                atomicMax(&segloc[go * DIM + 16 + m], enc_f32(z1));
            } else {
                atomicMax(&segmax[g * DIM + m], enc_f32(z0));
                atomicMax(&segmax[g * DIM + 16 + m], enc_f32(z1));
            }
        }
    }
    __syncthreads();
    unsigned v = segloc[t];
    if (v) atomicMax(&segmax[(gfirst + (t >> 5)) * DIM + (t & 31)], v);
}

// out[g][j] += decode(segmax[g][j]); reset segmax for the next layer's atomics.
__global__ void add_out_kernel(unsigned* __restrict__ segmax, float* __restrict__ out) {
    int t = blockIdx.x * blockDim.x + threadIdx.x;  // 2048
    out[t] += dec_f32(segmax[t]);
    segmax[t] = 0;
}

extern "C" void kernel_launch(void* const* d_in, const int* in_sizes, int n_in,
                              void* d_out, int out_size, void* d_ws, size_t ws_size,
                              hipStream_t stream) {
    const float* x0        = (const float*)d_in[0];
    const int*   ei        = (const int*)d_in[1];     // (2,E): row0=src, row1=dst
    const int*   batch     = (const int*)d_in[2];
    const float* lw        = (const float*)d_in[3];
    const float* lin_W     = (const float*)d_in[4];
    const float* lin_b     = (const float*)d_in[5];
    const float* lin_gamma = (const float*)d_in[6];
    const float* lin_beta  = (const float*)d_in[7];
    const float* lin_mean  = (const float*)d_in[8];
    const float* lin_var   = (const float*)d_in[9];
    const float* conv_W    = (const float*)d_in[10];
    const float* conv_b    = (const float*)d_in[11];
    const float* conv_gamma= (const float*)d_in[12];
    const float* conv_beta = (const float*)d_in[13];
    const float* conv_mean = (const float*)d_in[14];
    const float* conv_var  = (const float*)d_in[15];

    float* out  = (float*)d_out;                 // [G*32]
    float* Z    = out + N_GROUPS * DIM;          // [N*32]
    float* xout = Z + (size_t)N_NODES * DIM;     // [N*32] final x (fp32 conv out, layer 2)

    char* p = (char*)d_ws;
    unsigned short* x0b     = (unsigned short*)p; p += ((size_t)N_NODES * DIM + 8192) * sizeof(unsigned short);
    unsigned short* xbufb   = (unsigned short*)p; p += ((size_t)N_NODES * DIM + 8192) * sizeof(unsigned short);
    unsigned*       binbuf  = (unsigned*)p;       p += (size_t)N_EDGES * sizeof(unsigned);
    int*            esrc    = (int*)p;            p += (size_t)N_EDGES * sizeof(int);
    int*            nodeptr = (int*)p;            p += (NBINS * BIN_NODES + 1) * sizeof(int);
    int*            blockcnt= (int*)p;            p += (size_t)HIST_BLOCKS * NBINS * sizeof(int);
    int*            bincnt  = (int*)p;            p += NBINS * sizeof(int);
    int*            binoff  = (int*)p;            p += (NBINS + 1) * sizeof(int);
    int*            bincur  = (int*)p;            p += NBINS * sizeof(int);
    unsigned*       segmx   = (unsigned*)p;       p += N_GROUPS * DIM * sizeof(unsigned);
    float*          Wf      = (float*)p;          p += 5 * DIM * DIM * sizeof(float);
    float*          shf     = (float*)p;          p += 5 * DIM * sizeof(float);
    unsigned short* Wfb     = (unsigned short*)p; p += 5 * DIM * DIM * sizeof(unsigned short);

    const int* src = ei;
    const int* dst = ei + N_EDGES;

    const int linZ_blocks = (N_NODES + LINM_ROWS_PER_BLOCK - 1) / LINM_ROWS_PER_BLOCK;  // 391
    const int gf_blocks   = (N_NODES + 63) / 64;                                        // 1563
    const int cvt_blocks  = N_NODES * DIM / 4 / 256;                                    // 3125

    hipMemsetAsync(out, 0, N_GROUPS * DIM * sizeof(float), stream);
    hipMemsetAsync(bincnt, 0, NBINS * sizeof(int), stream);
    hipMemsetAsync(segmx, 0, N_GROUPS * DIM * sizeof(unsigned), stream);
    fold_kernel<<<5, 1024, 0, stream>>>(lin_W, lin_b, lin_gamma, lin_beta, lin_mean, lin_var,
                                        conv_W, conv_b, conv_gamma, conv_beta, conv_mean, conv_var,
                                        Wf, shf, Wfb);

    // ---- CSR build + bf16 copy of x0 ----
    binhist_kernel<<<HIST_BLOCKS, 256, 0, stream>>>(dst, bincnt, blockcnt);
    binscan_kernel<<<1, 1024, 0, stream>>>(bincnt, binoff, bincur);
    binscatter_kernel<<<HIST_BLOCKS, 256, 0, stream>>>(src, dst, bincur, binbuf, blockcnt);
    binsort_kernel<<<NBINS, 256, 0, stream>>>(binbuf, binoff, esrc, nodeptr);
    convert_kernel<<<cvt_blocks, 256, 0, stream>>>(x0, x0b);

    // ---- layer 0 ----
    linZ_first_kernel<<<linZ_blocks, 256, 0, stream>>>(x0b, Wfb, shf, batch, lw, Z, segmx);
    add_out_kernel<<<8, 256, 0, stream>>>(segmx, out);

    // ---- layer 1 (fully fused: gather + conv + lin + Z + segmax) ----
    gin_fused_kernel<<<gf_blocks, 256, 0, stream>>>(x0b, esrc, nodeptr,
                                                    Wfb + 3 * DIM * DIM, shf + 3 * DIM,
                                                    Wfb + 1 * DIM * DIM, shf + 1 * DIM,
                                                    batch, lw + 1,
                                                    xbufb, (float*)nullptr, Z, segmx);
    add_out_kernel<<<8, 256, 0, stream>>>(segmx, out);

    // ---- layer 2 ----
    gin_fused_kernel<<<gf_blocks, 256, 0, stream>>>(xbufb, esrc, nodeptr,
                                                    Wfb + 4 * DIM * DIM, shf + 4 * DIM,
                                                    Wfb + 2 * DIM * DIM, shf + 2 * DIM,
                                                    batch, lw + 2,
                                                    (unsigned short*)nullptr, xout, Z, segmx);
    add_out_kernel<<<8, 256, 0, stream>>>(segmx, out);
}